// Round 7
// baseline (43.858 us; speedup 1.0000x reference)
//
#include <hip/hip_runtime.h>
#include <hip/hip_bf16.h>

#define CIN 65
#define LIN 577
#define NSTEP 18      // K = 576 = 18 steps of 32; t_resc is a rank-1 epilogue
#define M_  16384

typedef __bf16 bf16x8 __attribute__((ext_vector_type(8)));
typedef float  f32x4  __attribute__((ext_vector_type(4)));
typedef unsigned short u16x8 __attribute__((ext_vector_type(8)));

// SIG[r] = flatten(rot90(arange(9).reshape(3,3), r)); SIG[(4-g)&3] = sigma_g^{-1}
__constant__ int SIG[4][9] = {
  {0,1,2,3,4,5,6,7,8},
  {2,5,8,1,4,7,0,3,6},
  {8,7,6,5,4,3,2,1,0},
  {6,3,0,7,4,1,8,5,2}};

// XOR mask for the 4 16B-chunks of a 64B LDS row (2-way max bank aliasing = free)
__device__ __forceinline__ int swzm(int r) { return (r ^ (r >> 2)) & 3; }

// ---- kernel 1 (fused): blocks [0,256): im2col -> A[q 72][row 16384][8] + T
//                        blocks [256,400): W -> Wg[g*18+ks][col 256][32] bf16
__global__ __launch_bounds__(512) void prep_k(const float* __restrict__ x,
                                              const float* __restrict__ W,
                                              __hip_bfloat16* __restrict__ A,
                                              __hip_bfloat16* __restrict__ Wg,
                                              float* __restrict__ T) {
  __shared__ float lds[CIN * 3 * 72];   // [c][dy][slot 4+u], u = x-pos in [-1,64]
  const int tid = threadIdx.x;
  if (blockIdx.x >= 256) {              // ---- weight prep branch ----
    int pidx = (blockIdx.x - 256) * 512 + tid;   // 0..73727
    int jc  = pidx & 3;
    int col = (pidx >> 2) & 255;
    int t   = pidx >> 10;               // g*18 + ks
    int ks  = t % NSTEP, g = t / NSTEP;
    int k   = SIG[(4 - g) & 3][ks >> 1];
    const float* src = W + col * LIN + 1 + k * 64 + (ks & 1) * 32 + jc * 8;
    u16x8 pk;
#pragma unroll
    for (int e = 0; e < 8; ++e) {
      union { __hip_bfloat16 h; unsigned short u; } cv;
      cv.h = __float2bfloat16(src[e]);
      pk[e] = cv.u;
    }
    *(u16x8*)(Wg + (size_t)pidx * 8) = pk;
    return;
  }
  // ---- im2col branch ----
  const int b = blockIdx.x >> 6, py = blockIdx.x & 63;
  const float* xb = x + (size_t)b * (CIN * 4096);
  for (int i = tid; i < CIN * 3 * 18; i += 512)
    *(f32x4*)&lds[i * 4] = (f32x4){0.f, 0.f, 0.f, 0.f};
  __syncthreads();
  for (int i = tid; i < CIN * 3 * 16; i += 512) {
    int pr = i >> 4, j = i & 15;
    int c = pr / 3, dy = pr - c * 3;
    int hy = py + dy - 1;
    if (hy >= 0 && hy < 64)
      *(f32x4*)&lds[c * 216 + dy * 72 + 4 + j * 4] =
          *(const f32x4*)(xb + c * 4096 + hy * 64 + j * 4);
  }
  __syncthreads();

  const int wave = tid >> 6, px = tid & 63;
  const int rowid = (blockIdx.x << 6) | px;
#pragma unroll
  for (int qi = 0; qi < 9; ++qi) {
    int q = wave * 9 + qi;               // q = m*8 + cb8 (chunk of 8 channels)
    int m = q >> 3, cb8 = q & 7;
    int dy = m / 3, dx = m - dy * 3;
    const float* src = &lds[(1 + cb8 * 8) * 216 + dy * 72 + 3 + dx + px];
    u16x8 pk;
#pragma unroll
    for (int e = 0; e < 8; ++e) {
      union { __hip_bfloat16 h; unsigned short u; } cv;
      cv.h = __float2bfloat16(src[e * 216]);
      pk[e] = cv.u;
    }
    *(u16x8*)(A + ((size_t)q * M_ + rowid) * 8) = pk;   // dense 16B/lane
  }
  if (wave == 0) {   // t_resc (rotation-invariant)
    float s = 0.f;
#pragma unroll
    for (int m = 0; m < 9; ++m) {
      float t = fmaxf(lds[(m / 3) * 72 + 3 + (m % 3) + px], 1.f);
      s += t * t;
    }
    T[rowid] = sqrtf(s - 8.f);
  }
}

// ---- kernel 2: GEMM BM=128 BN=256 BK=32; A global->reg (dbuf), B via LDS --
__device__ __forceinline__ void async_cp16(const void* g, void* ldsbase) {
  __builtin_amdgcn_global_load_lds(
      (const __attribute__((address_space(1))) void*)g,
      (__attribute__((address_space(3))) void*)ldsbase, 16, 0, 0);
}

__global__ __launch_bounds__(512, 4) void gemm_k(const __hip_bfloat16* __restrict__ A,
                                                 const __hip_bfloat16* __restrict__ Wg,
                                                 const float* __restrict__ W,
                                                 const float* __restrict__ bias,
                                                 const float* __restrict__ T,
                                                 float* __restrict__ out) {
  // B bufs: 0 / 16K / 32K (16 KB each) | Tsh @49152 (512 B) | Ps @49664 (2 KB)
  __shared__ __align__(16) char smem[51712];
  const int fid = blockIdx.x;
  const int lid = ((fid & 7) << 6) | (fid >> 3);   // XCD-contiguous, bijective
  const int g = lid & 3, rb = lid >> 2;
  const int brow = rb << 7;
  const int tid = threadIdx.x, wave = tid >> 6, lane = tid & 63;
  const int fr = lane & 15, fq = lane >> 4;
  const int wr = (wave >> 2) * 64, wcb = (wave & 3) * 64;

  float* Tsh = (float*)(smem + 49152);
  float* Ps  = (float*)(smem + 49664);
  if (tid < 128) Tsh[tid] = T[brow + tid];   // overlaps whole mainloop

  // B staging: LDS dest linear, global source chunk-permuted (rule #21)
  const int bcol0 = tid >> 2, blc0 = (tid & 3) ^ swzm(bcol0);
  const int bcol1 = 128 + (tid >> 2), blc1 = (tid & 3) ^ swzm(bcol1);
  const __hip_bfloat16* Wgg = Wg + ((size_t)(g * NSTEP) << 13);
  auto STAGE_B = [&](char* pb, int ks) {
    const __hip_bfloat16* bs = Wgg + ((size_t)ks << 13);
    async_cp16(bs + bcol0 * 32 + blc0 * 8, pb + wave * 1024);
    async_cp16(bs + bcol1 * 32 + blc1 * 8, pb + wave * 1024 + 8192);
  };

  // A fragments direct global->reg: chunk q = 4*ks + fq, row = brow+wr+i*16+fr
  // elem addr = (q*M_ + row)*8  ->  per-step stride M_*32 elems, per-i 128 elems
  const __hip_bfloat16* Arow = A + (((size_t)fq * M_ + brow + wr + fr) << 3);
  auto LOAD_A = [&](bf16x8* dst, int ks) {
#pragma unroll
    for (int i = 0; i < 4; ++i)
      dst[i] = *(const bf16x8*)(Arow + (size_t)ks * (M_ * 32) + i * 128);
  };

  f32x4 acc[4][4] = {};
  auto COMPUTE = [&](const char* Bb, const bf16x8* af) {
    bf16x8 bf[4];
#pragma unroll
    for (int j = 0; j < 4; ++j) {
      int c = wcb + j * 16 + fr;
      bf[j] = *(const bf16x8*)(Bb + c * 64 + ((fq ^ swzm(c)) << 4));
    }
    __builtin_amdgcn_s_setprio(1);
#pragma unroll
    for (int i = 0; i < 4; ++i)
#pragma unroll
      for (int j = 0; j < 4; ++j)
        acc[i][j] = __builtin_amdgcn_mfma_f32_16x16x32_bf16(af[i], bf[j], acc[i][j], 0, 0, 0);
    __builtin_amdgcn_s_setprio(0);
  };

  bf16x8 afA[4], afB[4];
  char *cB = smem, *nB = smem + 16384, *tB = smem + 32768;
  STAGE_B(cB, 0);
  STAGE_B(nB, 1);
  LOAD_A(afA, 0);

  for (int kp = 0; kp < NSTEP; kp += 2) {
    // ---- ks = kp (even): compute afA, prefetch afB(kp+1), stage B(kp+2) ----
    asm volatile("s_waitcnt vmcnt(6)" ::: "memory");   // B(kp) resident (own writes)
    __builtin_amdgcn_s_barrier();                      // all waves' B(kp) writes done
    if (kp + 2 < NSTEP) STAGE_B(tB, kp + 2);
    LOAD_A(afB, kp + 1);
    COMPUTE(cB, afA);
    { char* r = cB; cB = nB; nB = tB; tB = r; }
    // ---- ks = kp+1 (odd): compute afB, prefetch afA(kp+2), stage B(kp+3) ---
    if (kp + 1 < NSTEP - 1) {
      asm volatile("s_waitcnt vmcnt(6)" ::: "memory");
    } else {
      asm volatile("s_waitcnt vmcnt(4)" ::: "memory"); // last step: only A(17) newer
    }
    __builtin_amdgcn_s_barrier();
    if (kp + 3 < NSTEP) STAGE_B(tB, kp + 3);
    if (kp + 2 < NSTEP) LOAD_A(afA, kp + 2);
    COMPUTE(cB, afB);
    { char* r = cB; cB = nB; nB = tB; tB = r; }
  }
  __syncthreads();   // mainloop done; Tsh visible; Ps region usable

  // epilogue: y = acc + bias + t*W[:,0]; store y (o!=0); fused Lorentz norm
  float bo[4], w0v[4]; int oc[4];
#pragma unroll
  for (int j = 0; j < 4; ++j) {
    oc[j]  = wcb + j * 16 + fr;
    bo[j]  = bias[oc[j]];
    w0v[j] = W[oc[j] * LIN];
  }
#pragma unroll
  for (int i = 0; i < 4; ++i) {
#pragma unroll
    for (int rr = 0; rr < 4; ++rr) {
      int rl = wr + i * 16 + fq * 4 + rr;
      int row = brow + rl;
      size_t obase = ((size_t)(((row >> 12) * 4 + g) * 4096 + (row & 4095)) << 8);
      float tval = Tsh[rl];
      float s = 0.f;
#pragma unroll
      for (int j = 0; j < 4; ++j) {
        float y = acc[i][j][rr] + bo[j] + tval * w0v[j];
        if (oc[j] != 0) { s += y * y; out[obase + oc[j]] = y; }
      }
      s += __shfl_xor(s, 1); s += __shfl_xor(s, 2);
      s += __shfl_xor(s, 4); s += __shfl_xor(s, 8);
      if (fr == 0) Ps[rl * 4 + (wave & 3)] = s;
    }
  }
  __syncthreads();
  if (tid < 128) {
    int row = brow + tid;
    float s = Ps[tid * 4] + Ps[tid * 4 + 1] + Ps[tid * 4 + 2] + Ps[tid * 4 + 3] + 1.0f;
    out[(size_t)(((row >> 12) * 4 + g) * 4096 + (row & 4095)) << 8] = sqrtf(s);
  }
}

extern "C" void kernel_launch(void* const* d_in, const int* in_sizes, int n_in,
                              void* d_out, int out_size, void* d_ws, size_t ws_size,
                              hipStream_t stream) {
  const float* x    = (const float*)d_in[0];
  const float* W    = (const float*)d_in[1];
  const float* bias = (const float*)d_in[2];
  float* out = (float*)d_out;

  char* ws = (char*)d_ws;
  __hip_bfloat16* Wg = (__hip_bfloat16*)ws;                 // 73728*8*2 = 1179648 B
  float*          T  = (float*)(ws + 1179648);              // 65536 B
  __hip_bfloat16* A  = (__hip_bfloat16*)(ws + 1245184);     // 72*16384*8*2 = 18874368 B

  prep_k<<<400, 512, 0, stream>>>(x, W, A, Wg, T);
  gemm_k<<<512, 512, 0, stream>>>(A, Wg, W, bias, T, out);
}